// Round 1
// baseline (240.979 us; speedup 1.0000x reference)
//
#include <hip/hip_runtime.h>

// BoundaryLoss: B=2, C=3, D=H=W=96.
// Exact squared EDT via separable min-plus parabola convolution (fp32 exact:
// all surviving values are integers < 2^24). 8 fields: (b, class-1, polarity).
// polarity 0: init 0 where targets==c else BIG  -> dist_out = edt(~pos)
// polarity 1: init BIG where targets==c else 0  -> dist_in  = edt(pos)

#define NV 884736      // 96^3
#define NX 96
#define SLAB 9216      // 96*96
#define BIGF 1.0e8f
#define NF 8

__global__ __launch_bounds__(256) void init_masks(const int* __restrict__ targets,
                                                  float* __restrict__ F) {
    int idx = blockIdx.x * 256 + threadIdx.x;      // over 2*NV
    if (idx >= 2 * NV) return;
    int b = idx / NV, v = idx - b * NV;
    int t = targets[idx];
    float* Fb = F + (size_t)b * 4 * NV;
    bool m1 = (t == 1);
    Fb[v]              = m1 ? 0.0f : BIGF;
    Fb[(size_t)NV + v] = m1 ? BIGF : 0.0f;
    bool m2 = (t == 2);
    Fb[(size_t)2 * NV + v] = m2 ? 0.0f : BIGF;
    Fb[(size_t)3 * NV + v] = m2 ? BIGF : 0.0f;
}

// Pass along W (contiguous axis). Each block owns 8 full lines (768 elems).
__global__ __launch_bounds__(256) void pass_w(float* __restrict__ F) {
    __shared__ float lds[768];
    size_t base = (size_t)blockIdx.x * 768;
    int tid = threadIdx.x;
    #pragma unroll
    for (int k = 0; k < 3; ++k) lds[k * 256 + tid] = F[base + k * 256 + tid];
    __syncthreads();
    #pragma unroll
    for (int k = 0; k < 3; ++k) {
        int idx = k * 256 + tid;
        int i = idx % 96;
        int lo = idx - i;
        float fi = (float)i;
        float best = 2.0e8f;
        float jf = 0.0f;
        #pragma unroll 8
        for (int j = 0; j < 96; ++j) {
            float d = fi - jf;
            jf += 1.0f;
            best = fminf(best, fmaf(d, d, lds[lo + j]));
        }
        F[base + idx] = best;
    }
}

// Strided pass: lines run along stride STRIDE_J (length 96); block covers one
// (field, outer) pair and a 32-wide x tile; all 96 line positions in LDS.
template <int STRIDE_J, int STRIDE_O>
__global__ __launch_bounds__(256) void pass_s(float* __restrict__ F) {
    __shared__ float lds[96][32];
    int f = blockIdx.z;
    int o = blockIdx.y;
    int x0 = blockIdx.x * 32;
    size_t base = (size_t)f * NV + (size_t)o * STRIDE_O + x0;
    int tid = threadIdx.x;
    int xr = tid & 31;
    int r0 = tid >> 5;                     // 0..7
    #pragma unroll
    for (int k = 0; k < 12; ++k) {
        int j = k * 8 + r0;
        lds[j][xr] = F[base + (size_t)j * STRIDE_J + xr];
    }
    __syncthreads();
    #pragma unroll
    for (int k = 0; k < 12; ++k) {
        int i = k * 8 + r0;
        float fi = (float)i;
        float best = 2.0e8f;
        float jf = 0.0f;
        #pragma unroll 8
        for (int j = 0; j < 96; ++j) {
            float d = fi - jf;
            jf += 1.0f;
            best = fminf(best, fmaf(d, d, lds[j][xr]));
        }
        F[base + (size_t)i * STRIDE_J + xr] = best;
    }
}

__global__ __launch_bounds__(256) void reduce_k(const float* __restrict__ logits,
                                                const float* __restrict__ F,
                                                double* __restrict__ acc) {
    int idx = blockIdx.x * 256 + threadIdx.x;      // over 2*NV (exact)
    float contrib = 0.0f;
    if (idx < 2 * NV) {
        int b = idx / NV, v = idx - b * NV;
        size_t lbase = (size_t)b * 3 * NV + v;
        float l0 = logits[lbase];
        float l1 = logits[lbase + NV];
        float l2 = logits[lbase + 2 * (size_t)NV];
        float m = fmaxf(l0, fmaxf(l1, l2));
        float e0 = expf(l0 - m), e1 = expf(l1 - m), e2 = expf(l2 - m);
        float inv = 1.0f / (e0 + e1 + e2);
        const float* Fb = F + (size_t)b * 4 * NV;
        float sd1 = sqrtf(Fb[v]) - sqrtf(Fb[(size_t)NV + v]);
        float sd2 = sqrtf(Fb[2 * (size_t)NV + v]) - sqrtf(Fb[3 * (size_t)NV + v]);
        contrib = (e1 * sd1 + e2 * sd2) * inv;
    }
    // wave (64) shuffle reduce, then cross-wave via LDS
    float s = contrib;
    #pragma unroll
    for (int off = 32; off > 0; off >>= 1) s += __shfl_down(s, off, 64);
    __shared__ float wsum[4];
    if ((threadIdx.x & 63) == 0) wsum[threadIdx.x >> 6] = s;
    __syncthreads();
    if (threadIdx.x == 0) {
        float t = wsum[0] + wsum[1] + wsum[2] + wsum[3];
        atomicAdd(acc, (double)t);
    }
}

__global__ void finalize(const double* __restrict__ acc, float* __restrict__ out) {
    out[0] = (float)(acc[0] / ((double)NV * 2.0));   // mean over DHW, then /B
}

extern "C" void kernel_launch(void* const* d_in, const int* in_sizes, int n_in,
                              void* d_out, int out_size, void* d_ws, size_t ws_size,
                              hipStream_t stream) {
    const float* logits = (const float*)d_in[0];
    const int* targets = (const int*)d_in[1];
    float* out = (float*)d_out;

    double* acc = (double*)d_ws;
    float* F = (float*)((char*)d_ws + 256);           // 8 * NV floats = 28.3 MB

    hipMemsetAsync(acc, 0, sizeof(double), stream);
    init_masks<<<(2 * NV + 255) / 256, 256, 0, stream>>>(targets, F);
    pass_w<<<NF * NV / 768, 256, 0, stream>>>(F);                       // 9216 blocks
    pass_s<96, SLAB><<<dim3(3, 96, NF), 256, 0, stream>>>(F);           // along H
    pass_s<SLAB, 96><<<dim3(3, 96, NF), 256, 0, stream>>>(F);           // along D
    reduce_k<<<(2 * NV) / 256, 256, 0, stream>>>(logits, F, acc);
    finalize<<<1, 1, 0, stream>>>(acc, out);
}

// Round 2
// 143.172 us; speedup vs baseline: 1.6831x; 1.6831x over previous
//
#include <hip/hip_runtime.h>

// BoundaryLoss: B=2, C=3, D=H=W=96.
// Exact squared EDT via separable min-plus parabola convolution (fp32 exact).
// 8 fields f = b*4 + {c1_out, c1_in, c2_out, c2_in}:
//   pol 0 (dist_out): zeros where t==c  -> edt(~pos) squared
//   pol 1 (dist_in) : zeros where t!=c  -> edt(pos) squared
// Pass 1 (W axis) on binary data = nearest-set-bit query on a 96-bit mask.

#define NV 884736      // 96^3
#define SLAB 9216      // 96*96
#define BIGF 1.0e8f
#define NF 8
#define NBLK_RED 6912  // 2*NV / 256

__device__ __forceinline__ float dist2_96(unsigned long long lo, unsigned long long hi, int i) {
    unsigned __int128 m = ((unsigned __int128)hi << 64) | lo;
    unsigned __int128 r = m >> i;
    unsigned long long rlo = (unsigned long long)r;
    unsigned long long rhi = (unsigned long long)(r >> 64);
    int right = rlo ? __builtin_ctzll(rlo) : (rhi ? 64 + __builtin_ctzll(rhi) : (1 << 20));
    unsigned __int128 s = m << (127 - i);
    unsigned long long shi = (unsigned long long)(s >> 64);
    unsigned long long slo = (unsigned long long)s;
    int left = shi ? __builtin_clzll(shi) : (slo ? 64 + __builtin_clzll(slo) : (1 << 20));
    int d = right < left ? right : left;
    if (d >= (1 << 20)) return BIGF;
    return (float)(d * d);
}

// Fused: build binary masks from targets and do the W-axis (contiguous) pass
// via nearest-set-bit. Block = 8 lines (768 elems); grid = (1152, B).
__global__ __launch_bounds__(256) void init_pass_w(const int* __restrict__ targets,
                                                   float* __restrict__ F) {
    __shared__ int t_lds[768];
    __shared__ unsigned long long zm[8][4];   // per line: z1lo, z1hi, z2lo, z2hi
    int b = blockIdx.y;
    int group = blockIdx.x;                   // 0..1151
    int tid = threadIdx.x;
    size_t tbase = (size_t)b * NV + (size_t)group * 768;
    #pragma unroll
    for (int k = 0; k < 3; ++k) t_lds[k * 256 + tid] = targets[tbase + k * 256 + tid];
    __syncthreads();
    if (tid < 8) {
        unsigned long long z1lo = 0, z1hi = 0, z2lo = 0, z2hi = 0;
        const int* tl = &t_lds[tid * 96];
        for (int j = 0; j < 64; ++j) {
            unsigned long long bit = 1ULL << j;
            int t = tl[j];
            if (t == 1) z1lo |= bit; else if (t == 2) z2lo |= bit;
        }
        for (int j = 64; j < 96; ++j) {
            unsigned long long bit = 1ULL << (j - 64);
            int t = tl[j];
            if (t == 1) z1hi |= bit; else if (t == 2) z2hi |= bit;
        }
        zm[tid][0] = z1lo; zm[tid][1] = z1hi; zm[tid][2] = z2lo; zm[tid][3] = z2hi;
    }
    __syncthreads();
    float* Fb = F + (size_t)b * 4 * NV + (size_t)group * 768;
    const unsigned long long HM = 0xFFFFFFFFULL;   // valid bits 64..95 in hi
    #pragma unroll
    for (int k = 0; k < 3; ++k) {
        int idx = k * 256 + tid;
        int l = idx / 96, i = idx - l * 96;
        unsigned long long z1lo = zm[l][0], z1hi = zm[l][1];
        unsigned long long z2lo = zm[l][2], z2hi = zm[l][3];
        Fb[idx]                  = dist2_96(z1lo, z1hi, i);
        Fb[(size_t)NV + idx]     = dist2_96(~z1lo, ~z1hi & HM, i);
        Fb[2 * (size_t)NV + idx] = dist2_96(z2lo, z2hi, i);
        Fb[3 * (size_t)NV + idx] = dist2_96(~z2lo, ~z2hi & HM, i);
    }
}

// Strided pass: lines along stride STRIDE_J (length 96); block = one (field,
// outer) pair x 32-wide tile; 96 line positions in LDS. 3-op inner loop.
template <int STRIDE_J, int STRIDE_O>
__global__ __launch_bounds__(256) void pass_s(float* __restrict__ F) {
    __shared__ float lds[96][32];
    int f = blockIdx.z;
    int o = blockIdx.y;
    int x0 = blockIdx.x * 32;
    size_t base = (size_t)f * NV + (size_t)o * STRIDE_O + x0;
    int tid = threadIdx.x;
    int xr = tid & 31;
    int r0 = tid >> 5;                     // 0..7
    #pragma unroll
    for (int k = 0; k < 12; ++k) {
        int j = k * 8 + r0;
        lds[j][xr] = F[base + (size_t)j * STRIDE_J + xr];
    }
    __syncthreads();
    #pragma unroll
    for (int k = 0; k < 12; ++k) {
        int i = k * 8 + r0;
        float best = 2.0e8f;
        float d = (float)i;
        #pragma unroll 8
        for (int j = 0; j < 96; ++j) {
            best = fminf(best, fmaf(d, d, lds[j][xr]));
            d -= 1.0f;
        }
        F[base + (size_t)i * STRIDE_J + xr] = best;
    }
}

__global__ __launch_bounds__(256) void reduce_k(const float* __restrict__ logits,
                                                const float* __restrict__ F,
                                                double* __restrict__ partials) {
    int idx = blockIdx.x * 256 + threadIdx.x;      // over 2*NV (exact)
    int b = idx / NV, v = idx - b * NV;
    size_t lbase = (size_t)b * 3 * NV + v;
    float l0 = logits[lbase];
    float l1 = logits[lbase + NV];
    float l2 = logits[lbase + 2 * (size_t)NV];
    float m = fmaxf(l0, fmaxf(l1, l2));
    float e0 = expf(l0 - m), e1 = expf(l1 - m), e2 = expf(l2 - m);
    float inv = 1.0f / (e0 + e1 + e2);
    const float* Fb = F + (size_t)b * 4 * NV;
    float sd1 = sqrtf(Fb[v]) - sqrtf(Fb[(size_t)NV + v]);
    float sd2 = sqrtf(Fb[2 * (size_t)NV + v]) - sqrtf(Fb[3 * (size_t)NV + v]);
    float s = (e1 * sd1 + e2 * sd2) * inv;
    #pragma unroll
    for (int off = 32; off > 0; off >>= 1) s += __shfl_down(s, off, 64);
    __shared__ float wsum[4];
    if ((threadIdx.x & 63) == 0) wsum[threadIdx.x >> 6] = s;
    __syncthreads();
    if (threadIdx.x == 0)
        partials[blockIdx.x] = (double)(wsum[0] + wsum[1] + wsum[2] + wsum[3]);
}

__global__ __launch_bounds__(256) void final_reduce(const double* __restrict__ partials,
                                                    float* __restrict__ out) {
    double s = 0.0;
    for (int i = threadIdx.x; i < NBLK_RED; i += 256) s += partials[i];
    #pragma unroll
    for (int off = 32; off > 0; off >>= 1) s += __shfl_down(s, off, 64);
    __shared__ double wsum[4];
    if ((threadIdx.x & 63) == 0) wsum[threadIdx.x >> 6] = s;
    __syncthreads();
    if (threadIdx.x == 0)
        out[0] = (float)((wsum[0] + wsum[1] + wsum[2] + wsum[3]) / ((double)NV * 2.0));
}

extern "C" void kernel_launch(void* const* d_in, const int* in_sizes, int n_in,
                              void* d_out, int out_size, void* d_ws, size_t ws_size,
                              hipStream_t stream) {
    const float* logits = (const float*)d_in[0];
    const int* targets = (const int*)d_in[1];
    float* out = (float*)d_out;

    double* partials = (double*)d_ws;                 // 6912 doubles = 55.3 KB
    float* F = (float*)((char*)d_ws + 65536);         // 8 * NV floats = 28.3 MB

    init_pass_w<<<dim3(1152, 2), 256, 0, stream>>>(targets, F);
    pass_s<96, SLAB><<<dim3(3, 96, NF), 256, 0, stream>>>(F);   // along H
    pass_s<SLAB, 96><<<dim3(3, 96, NF), 256, 0, stream>>>(F);   // along D
    reduce_k<<<NBLK_RED, 256, 0, stream>>>(logits, F, partials);
    final_reduce<<<1, 256, 0, stream>>>(partials, out);
}

// Round 3
// 98.864 us; speedup vs baseline: 2.4375x; 1.4482x over previous
//
#include <hip/hip_runtime.h>

// BoundaryLoss: B=2, C=3, D=H=W=96.
// Exact squared EDT via separable min-plus parabola convolution.
// Only 3 fields per batch: D_c = squared dist to nearest class-c voxel.
//   edt(~pos_c) = sqrt(D_c);  edt(pos_c) = sqrt(min of other two D's)
// (min-plus conv distributes over pointwise min, so per-class EDTs suffice.)
// Pass W: nearest-set-bit on 96-bit masks (binary input).
// Pass H, D: linearized parabola: stage ld[j]=f[j]+j^2, then
//   g[i] = i^2 + min_j fma(-2i, j, ld[j])   -- 1 fma + 0.5 min per elem-j.
// All surviving values are exact integers < 2^24 -> bitwise-exact vs ref.

#define NV 884736      // 96^3
#define SLAB 9216      // 96*96
#define BIGF 1.0e8f
#define NBLK_P2 1152

__device__ __forceinline__ float dist2_96(unsigned long long lo, unsigned long long hi, int i) {
    unsigned __int128 m = ((unsigned __int128)hi << 64) | lo;
    unsigned __int128 r = m >> i;
    unsigned long long rlo = (unsigned long long)r;
    unsigned long long rhi = (unsigned long long)(r >> 64);
    int right = rlo ? __builtin_ctzll(rlo) : (rhi ? 64 + __builtin_ctzll(rhi) : (1 << 20));
    unsigned __int128 s = m << (127 - i);
    unsigned long long shi = (unsigned long long)(s >> 64);
    unsigned long long slo = (unsigned long long)s;
    int left = shi ? __builtin_clzll(shi) : (slo ? 64 + __builtin_clzll(slo) : (1 << 20));
    int d = right < left ? right : left;
    if (d >= (1 << 20)) return BIGF;
    return (float)(d * d);
}

// Fused mask-build + W-axis pass. Block = 8 lines (768 elems); grid (1152, B).
__global__ __launch_bounds__(256) void init_pass_w(const int* __restrict__ targets,
                                                   float* __restrict__ F) {
    __shared__ int t_lds[768];
    __shared__ unsigned long long zm[8][6];   // z0lo,z0hi,z1lo,z1hi,z2lo,z2hi
    int b = blockIdx.y;
    int group = blockIdx.x;
    int tid = threadIdx.x;
    size_t tbase = (size_t)b * NV + (size_t)group * 768;
    #pragma unroll
    for (int k = 0; k < 3; ++k) t_lds[k * 256 + tid] = targets[tbase + k * 256 + tid];
    __syncthreads();
    if (tid < 8) {
        unsigned long long z0lo = 0, z0hi = 0, z1lo = 0, z1hi = 0, z2lo = 0, z2hi = 0;
        const int* tl = &t_lds[tid * 96];
        for (int j = 0; j < 64; ++j) {
            unsigned long long bit = 1ULL << j;
            int t = tl[j];
            if (t == 0) z0lo |= bit; else if (t == 1) z1lo |= bit; else z2lo |= bit;
        }
        for (int j = 64; j < 96; ++j) {
            unsigned long long bit = 1ULL << (j - 64);
            int t = tl[j];
            if (t == 0) z0hi |= bit; else if (t == 1) z1hi |= bit; else z2hi |= bit;
        }
        zm[tid][0] = z0lo; zm[tid][1] = z0hi;
        zm[tid][2] = z1lo; zm[tid][3] = z1hi;
        zm[tid][4] = z2lo; zm[tid][5] = z2hi;
    }
    __syncthreads();
    float* Fb = F + (size_t)b * 3 * NV + (size_t)group * 768;
    #pragma unroll
    for (int k = 0; k < 3; ++k) {
        int idx = k * 256 + tid;
        int l = idx / 96, i = idx - l * 96;
        Fb[idx]                  = dist2_96(zm[l][0], zm[l][1], i);
        Fb[(size_t)NV + idx]     = dist2_96(zm[l][2], zm[l][3], i);
        Fb[2 * (size_t)NV + idx] = dist2_96(zm[l][4], zm[l][5], i);
    }
}

// H-axis pass. Lines along stride 96. Block: 32 w-cols x 96 rows, one field.
// Grid (3, 96, 6): x-tile, d-index, field.
__global__ __launch_bounds__(256) void pass_h(float* __restrict__ F) {
    __shared__ float lds[32][98];             // transposed, padded for b64 align
    int f = blockIdx.z;
    int o = blockIdx.y;                       // d index
    int x0 = blockIdx.x * 32;
    int tid = threadIdx.x;
    int xr = tid & 31;
    int r0 = tid >> 5;                        // 0..7
    size_t base = (size_t)f * NV + (size_t)o * SLAB + x0;
    #pragma unroll
    for (int k = 0; k < 12; ++k) {
        int j = k * 8 + r0;
        float v = F[base + (size_t)j * 96 + xr];
        lds[xr][j] = fmaf((float)j, (float)j, v);
    }
    __syncthreads();
    float best[12];
    float coef[12];
    #pragma unroll
    for (int k = 0; k < 12; ++k) {
        best[k] = 2.0e8f;
        coef[k] = -2.0f * (float)(k * 8 + r0);
    }
    const float* lp = &lds[xr][0];
    float j0 = 0.0f, j1 = 1.0f;
    #pragma unroll 6
    for (int j = 0; j < 96; j += 2) {
        float2 ld = *(const float2*)(lp + j);
        #pragma unroll
        for (int k = 0; k < 12; ++k) {
            float v0 = fmaf(coef[k], j0, ld.x);
            float v1 = fmaf(coef[k], j1, ld.y);
            best[k] = fminf(best[k], fminf(v0, v1));
        }
        j0 += 2.0f; j1 += 2.0f;
    }
    #pragma unroll
    for (int k = 0; k < 12; ++k) {
        int i = k * 8 + r0;
        F[base + (size_t)i * 96 + xr] = fmaf((float)i, (float)i, best[k]);
    }
}

// D-axis pass fused with softmax/sqrt/reduction epilogue.
// Lines along stride SLAB. Block: 16 w-cols x 96 rows x 3 classes, one batch.
// Grid (6, 96, 2): x-tile, h-index, batch.
__global__ __launch_bounds__(256) void pass_d_reduce(const float* __restrict__ logits,
                                                     const float* __restrict__ F,
                                                     double* __restrict__ partials) {
    __shared__ float lds[3][16][98];
    int b = blockIdx.z;
    int o = blockIdx.y;                       // h index
    int x0 = blockIdx.x * 16;
    int tid = threadIdx.x;
    int xr = tid & 15;
    int rr = tid >> 4;                        // 0..15
    size_t fbase = (size_t)b * 3 * NV + (size_t)o * 96 + x0;
    #pragma unroll
    for (int m = 0; m < 18; ++m) {
        int c = m / 6;
        int j = (m % 6) * 16 + rr;
        float v = F[fbase + (size_t)c * NV + (size_t)j * SLAB + xr];
        lds[c][xr][j] = fmaf((float)j, (float)j, v);
    }
    __syncthreads();
    float best[3][6];
    float coef[6];
    #pragma unroll
    for (int k = 0; k < 6; ++k) {
        coef[k] = -2.0f * (float)(k * 16 + rr);
        best[0][k] = 2.0e8f; best[1][k] = 2.0e8f; best[2][k] = 2.0e8f;
    }
    const float* l0 = &lds[0][xr][0];
    const float* l1 = &lds[1][xr][0];
    const float* l2 = &lds[2][xr][0];
    float j0 = 0.0f, j1 = 1.0f;
    #pragma unroll 4
    for (int j = 0; j < 96; j += 2) {
        float2 a = *(const float2*)(l0 + j);
        float2 bb = *(const float2*)(l1 + j);
        float2 cc = *(const float2*)(l2 + j);
        #pragma unroll
        for (int k = 0; k < 6; ++k) {
            best[0][k] = fminf(best[0][k], fminf(fmaf(coef[k], j0, a.x),  fmaf(coef[k], j1, a.y)));
            best[1][k] = fminf(best[1][k], fminf(fmaf(coef[k], j0, bb.x), fmaf(coef[k], j1, bb.y)));
            best[2][k] = fminf(best[2][k], fminf(fmaf(coef[k], j0, cc.x), fmaf(coef[k], j1, cc.y)));
        }
        j0 += 2.0f; j1 += 2.0f;
    }
    float contrib = 0.0f;
    #pragma unroll
    for (int k = 0; k < 6; ++k) {
        int i = k * 16 + rr;
        float i2 = (float)(i * i);
        float sd1 = sqrtf(i2 + best[1][k]) - sqrtf(i2 + fminf(best[0][k], best[2][k]));
        float sd2 = sqrtf(i2 + best[2][k]) - sqrtf(i2 + fminf(best[0][k], best[1][k]));
        size_t lbase = (size_t)b * 3 * NV + (size_t)i * SLAB + (size_t)o * 96 + x0 + xr;
        float L0 = logits[lbase];
        float L1 = logits[lbase + NV];
        float L2 = logits[lbase + 2 * (size_t)NV];
        float mx = fmaxf(L0, fmaxf(L1, L2));
        float e0 = expf(L0 - mx), e1 = expf(L1 - mx), e2 = expf(L2 - mx);
        contrib += (e1 * sd1 + e2 * sd2) / (e0 + e1 + e2);
    }
    float s = contrib;
    #pragma unroll
    for (int off = 32; off > 0; off >>= 1) s += __shfl_down(s, off, 64);
    __shared__ float wsum[4];
    if ((tid & 63) == 0) wsum[tid >> 6] = s;
    __syncthreads();
    if (tid == 0) {
        int bid = blockIdx.x + 6 * blockIdx.y + 576 * blockIdx.z;
        partials[bid] = (double)(wsum[0] + wsum[1] + wsum[2] + wsum[3]);
    }
}

__global__ __launch_bounds__(256) void final_reduce(const double* __restrict__ partials,
                                                    float* __restrict__ out) {
    double s = 0.0;
    for (int i = threadIdx.x; i < NBLK_P2; i += 256) s += partials[i];
    #pragma unroll
    for (int off = 32; off > 0; off >>= 1) s += __shfl_down(s, off, 64);
    __shared__ double wsum[4];
    if ((threadIdx.x & 63) == 0) wsum[threadIdx.x >> 6] = s;
    __syncthreads();
    if (threadIdx.x == 0)
        out[0] = (float)((wsum[0] + wsum[1] + wsum[2] + wsum[3]) / ((double)NV * 2.0));
}

extern "C" void kernel_launch(void* const* d_in, const int* in_sizes, int n_in,
                              void* d_out, int out_size, void* d_ws, size_t ws_size,
                              hipStream_t stream) {
    const float* logits = (const float*)d_in[0];
    const int* targets = (const int*)d_in[1];
    float* out = (float*)d_out;

    double* partials = (double*)d_ws;                 // 1152 doubles
    float* F = (float*)((char*)d_ws + 65536);         // 6 * NV floats = 21.2 MB

    init_pass_w<<<dim3(1152, 2), 256, 0, stream>>>(targets, F);
    pass_h<<<dim3(3, 96, 6), 256, 0, stream>>>(F);
    pass_d_reduce<<<dim3(6, 96, 2), 256, 0, stream>>>(logits, F, partials);
    final_reduce<<<1, 256, 0, stream>>>(partials, out);
}